// Round 1
// baseline (852.151 us; speedup 1.0000x reference)
//
#include <hip/hip_runtime.h>

#define IN_DIM 128
#define HID 32
#define HEADS 4
#define OUTC (HEADS*HID)   // 128
#define NEG_SLOPE 0.2f

// ---------------------------------------------------------------------------
// K1: fused per-head projections Q,K,V = h @ W{q,k,v}   ([N,128] x [128,128])
// Block = 128 threads (one output column each), 32 rows per block.
// h tile staged in LDS; W streamed from L2 (196KB total, broadcast across blocks).
// ---------------------------------------------------------------------------
__global__ __launch_bounds__(128) void gat_proj(
    const float* __restrict__ h,
    const float* __restrict__ Wq,
    const float* __restrict__ Wk,
    const float* __restrict__ Wv,
    float* __restrict__ Q, float* __restrict__ K, float* __restrict__ V,
    int n)
{
    __shared__ float hs[32][IN_DIM];
    const int c    = threadIdx.x;        // 0..127 output column (= head*32 + d)
    const int row0 = blockIdx.x * 32;

    for (int idx = threadIdx.x; idx < 32 * IN_DIM; idx += blockDim.x) {
        int r = idx >> 7, cc = idx & 127;
        int gr = row0 + r;
        hs[r][cc] = (gr < n) ? h[(size_t)gr * IN_DIM + cc] : 0.f;
    }
    __syncthreads();

    const int head = c >> 5, dcol = c & 31;
    const float* wqp = Wq + (size_t)head * IN_DIM * HID + dcol;
    const float* wkp = Wk + (size_t)head * IN_DIM * HID + dcol;
    const float* wvp = Wv + (size_t)head * IN_DIM * HID + dcol;

    float accq[32], acck[32], accv[32];
#pragma unroll
    for (int r = 0; r < 32; ++r) { accq[r] = 0.f; acck[r] = 0.f; accv[r] = 0.f; }

    for (int i = 0; i < IN_DIM; ++i) {
        float wq = wqp[(size_t)i * HID];
        float wk = wkp[(size_t)i * HID];
        float wv = wvp[(size_t)i * HID];
#pragma unroll
        for (int r = 0; r < 32; ++r) {
            float hv = hs[r][i];          // wave-uniform -> LDS broadcast
            accq[r] = fmaf(hv, wq, accq[r]);
            acck[r] = fmaf(hv, wk, acck[r]);
            accv[r] = fmaf(hv, wv, accv[r]);
        }
    }

#pragma unroll
    for (int r = 0; r < 32; ++r) {
        int gr = row0 + r;
        if (gr < n) {
            size_t o = (size_t)gr * OUTC + c;
            Q[o] = accq[r];
            K[o] = acck[r];
            V[o] = accv[r];
        }
    }
}

// ---------------------------------------------------------------------------
// K2: one pass over edges. 32 lanes per edge.
//   scores s_h = dot32(q[src,h], k[dst,h]); ex = exp(leaky_relu(s))
//   denom[dst,h]   += ex          (4 atomics / edge)
//   out[dst, h*32+d] += ex * v[src, h*32+d]   (128 atomics / edge, coalesced)
// No segment-max pass: scores bounded ~|s|<40 -> exp safe in f32.
// ---------------------------------------------------------------------------
__global__ __launch_bounds__(256) void gat_edge(
    const int* __restrict__ src, const int* __restrict__ dst,
    const float* __restrict__ Q, const float* __restrict__ K,
    const float* __restrict__ V,
    float* __restrict__ out, float* __restrict__ denom, int nedges)
{
    int gid = blockIdx.x * blockDim.x + threadIdx.x;
    int e   = gid >> 5;
    if (e >= nedges) return;
    const int lane = threadIdx.x & 31;

    const int s = src[e];
    const int d = dst[e];

    const float* qs = Q + (size_t)s * OUTC;
    const float* kd = K + (size_t)d * OUTC;

    float p0 = qs[lane]      * kd[lane];
    float p1 = qs[32 + lane] * kd[32 + lane];
    float p2 = qs[64 + lane] * kd[64 + lane];
    float p3 = qs[96 + lane] * kd[96 + lane];

#pragma unroll
    for (int off = 16; off >= 1; off >>= 1) {
        p0 += __shfl_xor(p0, off, 32);
        p1 += __shfl_xor(p1, off, 32);
        p2 += __shfl_xor(p2, off, 32);
        p3 += __shfl_xor(p3, off, 32);
    }

    float e0 = __expf(p0 > 0.f ? p0 : NEG_SLOPE * p0);
    float e1 = __expf(p1 > 0.f ? p1 : NEG_SLOPE * p1);
    float e2 = __expf(p2 > 0.f ? p2 : NEG_SLOPE * p2);
    float e3 = __expf(p3 > 0.f ? p3 : NEG_SLOPE * p3);

    if (lane < 4) {
        float ev = (lane == 0) ? e0 : (lane == 1) ? e1 : (lane == 2) ? e2 : e3;
        atomicAdd(&denom[(size_t)d * HEADS + lane], ev);
    }

    const float* vs = V + (size_t)s * OUTC;
    float* od = out + (size_t)d * OUTC;

    atomicAdd(&od[lane],      e0 * vs[lane]);
    atomicAdd(&od[32 + lane], e1 * vs[32 + lane]);
    atomicAdd(&od[64 + lane], e2 * vs[64 + lane]);
    atomicAdd(&od[96 + lane], e3 * vs[96 + lane]);
}

// ---------------------------------------------------------------------------
// K3: out[n, h*32+d] /= max(denom[n,h], 1e-9)
// ---------------------------------------------------------------------------
__global__ __launch_bounds__(256) void gat_norm(
    float* __restrict__ out, const float* __restrict__ denom, int total)
{
    int t = blockIdx.x * blockDim.x + threadIdx.x;
    if (t >= total) return;
    int n  = t >> 7;
    int hh = (t >> 5) & 3;
    float dd = denom[(size_t)n * HEADS + hh];
    out[t] = out[t] / fmaxf(dd, 1e-9f);
}

extern "C" void kernel_launch(void* const* d_in, const int* in_sizes, int n_in,
                              void* d_out, int out_size, void* d_ws, size_t ws_size,
                              hipStream_t stream) {
    const float* h   = (const float*)d_in[0];
    const int*   src = (const int*)d_in[1];
    const int*   dst = (const int*)d_in[2];
    const float* Wq  = (const float*)d_in[3];
    const float* Wk  = (const float*)d_in[4];
    const float* Wv  = (const float*)d_in[5];
    float* out = (float*)d_out;

    const int n  = in_sizes[0] / IN_DIM;   // 50000
    const int ne = in_sizes[1];            // 1.6M

    // workspace layout: Q | K | V | denom   (~77.6 MB)
    float* Q     = (float*)d_ws;
    float* K     = Q + (size_t)n * OUTC;
    float* V     = K + (size_t)n * OUTC;
    float* denom = V + (size_t)n * OUTC;

    hipMemsetAsync(out,   0, (size_t)n * OUTC  * sizeof(float), stream);
    hipMemsetAsync(denom, 0, (size_t)n * HEADS * sizeof(float), stream);

    gat_proj<<<(n + 31) / 32, 128, 0, stream>>>(h, Wq, Wk, Wv, Q, K, V, n);

    int egroups_per_block = 256 / 32;  // 8 edges per block
    int eblocks = (ne + egroups_per_block - 1) / egroups_per_block;
    gat_edge<<<eblocks, 256, 0, stream>>>(src, dst, Q, K, V, out, denom, ne);

    int total = n * OUTC;
    gat_norm<<<(total + 255) / 256, 256, 0, stream>>>(out, denom, total);
}

// Round 2
// 522.569 us; speedup vs baseline: 1.6307x; 1.6307x over previous
//
#include <hip/hip_runtime.h>

#define IN_DIM 128
#define HID 32
#define HEADS 4
#define OUTC (HEADS*HID)   // 128
#define NEG_SLOPE 0.2f

// ---------------------------------------------------------------------------
// K1: fused per-head projections Q,K,V = h @ W{q,k,v}   ([N,128] x [128,128])
// ---------------------------------------------------------------------------
__global__ __launch_bounds__(128) void gat_proj(
    const float* __restrict__ h,
    const float* __restrict__ Wq,
    const float* __restrict__ Wk,
    const float* __restrict__ Wv,
    float* __restrict__ Q, float* __restrict__ K, float* __restrict__ V,
    int n)
{
    __shared__ float hs[32][IN_DIM];
    const int c    = threadIdx.x;        // 0..127 output column (= head*32 + d)
    const int row0 = blockIdx.x * 32;

    for (int idx = threadIdx.x; idx < 32 * IN_DIM; idx += blockDim.x) {
        int r = idx >> 7, cc = idx & 127;
        int gr = row0 + r;
        hs[r][cc] = (gr < n) ? h[(size_t)gr * IN_DIM + cc] : 0.f;
    }
    __syncthreads();

    const int head = c >> 5, dcol = c & 31;
    const float* wqp = Wq + (size_t)head * IN_DIM * HID + dcol;
    const float* wkp = Wk + (size_t)head * IN_DIM * HID + dcol;
    const float* wvp = Wv + (size_t)head * IN_DIM * HID + dcol;

    float accq[32], acck[32], accv[32];
#pragma unroll
    for (int r = 0; r < 32; ++r) { accq[r] = 0.f; acck[r] = 0.f; accv[r] = 0.f; }

    for (int i = 0; i < IN_DIM; ++i) {
        float wq = wqp[(size_t)i * HID];
        float wk = wkp[(size_t)i * HID];
        float wv = wvp[(size_t)i * HID];
#pragma unroll
        for (int r = 0; r < 32; ++r) {
            float hv = hs[r][i];
            accq[r] = fmaf(hv, wq, accq[r]);
            acck[r] = fmaf(hv, wk, acck[r]);
            accv[r] = fmaf(hv, wv, accv[r]);
        }
    }

#pragma unroll
    for (int r = 0; r < 32; ++r) {
        int gr = row0 + r;
        if (gr < n) {
            size_t o = (size_t)gr * OUTC + c;
            Q[o] = accq[r];
            K[o] = acck[r];
            V[o] = accv[r];
        }
    }
}

// ---------------------------------------------------------------------------
// CSR build: histogram -> hierarchical exclusive scan -> scatter
// ---------------------------------------------------------------------------
__global__ __launch_bounds__(256) void gat_hist(
    const int* __restrict__ dst, int* __restrict__ count, int ne)
{
    int e = blockIdx.x * blockDim.x + threadIdx.x;
    if (e < ne) atomicAdd(&count[dst[e]], 1);
}

// per-256-block sums of count[]
__global__ __launch_bounds__(256) void gat_bsum(
    const int* __restrict__ count, int* __restrict__ bsum, int n)
{
    __shared__ int ws[4];
    int i = blockIdx.x * 256 + threadIdx.x;
    int v = (i < n) ? count[i] : 0;
#pragma unroll
    for (int off = 32; off >= 1; off >>= 1) v += __shfl_down(v, off, 64);
    if ((threadIdx.x & 63) == 0) ws[threadIdx.x >> 6] = v;
    __syncthreads();
    if (threadIdx.x == 0) bsum[blockIdx.x] = ws[0] + ws[1] + ws[2] + ws[3];
}

// exclusive scan of block sums (nb <= 256), single block
__global__ __launch_bounds__(256) void gat_scan_bsum(int* bsum, int nb)
{
    __shared__ int s[256];
    int t = threadIdx.x;
    int v = (t < nb) ? bsum[t] : 0;
    s[t] = v; __syncthreads();
    for (int off = 1; off < 256; off <<= 1) {
        int u = (t >= off) ? s[t - off] : 0;
        __syncthreads();
        s[t] += u;
        __syncthreads();
    }
    if (t < nb) bsum[t] = s[t] - v;   // exclusive
}

// final: row_start[i] = exclusive scan; cursor copy; row_start[n] = total
__global__ __launch_bounds__(256) void gat_scan_final(
    const int* __restrict__ count, const int* __restrict__ bsum,
    int* __restrict__ row_start, int* __restrict__ cursor, int n)
{
    __shared__ int s[256];
    int t = threadIdx.x;
    int i = blockIdx.x * 256 + t;
    int v = (i < n) ? count[i] : 0;
    s[t] = v; __syncthreads();
    for (int off = 1; off < 256; off <<= 1) {
        int u = (t >= off) ? s[t - off] : 0;
        __syncthreads();
        s[t] += u;
        __syncthreads();
    }
    int excl = s[t] - v + bsum[blockIdx.x];
    if (i < n) { row_start[i] = excl; cursor[i] = excl; }
    if (i == n - 1) row_start[n] = excl + v;
}

__global__ __launch_bounds__(256) void gat_scatter(
    const int* __restrict__ src, const int* __restrict__ dst,
    int* __restrict__ cursor, int* __restrict__ ssrc, int ne)
{
    int e = blockIdx.x * blockDim.x + threadIdx.x;
    if (e >= ne) return;
    int d = dst[e];
    int pos = atomicAdd(&cursor[d], 1);
    ssrc[pos] = src[e];
}

// ---------------------------------------------------------------------------
// K2: gather — one wave64 per dst node, k[dst] in registers, no atomics.
// lane handles output elems c = 2*lane, 2*lane+1 (same head = lane>>4).
// Per edge: float2 q[src], float2 v[src]; 16-lane shfl reduce -> head dot.
// ---------------------------------------------------------------------------
__global__ __launch_bounds__(256) void gat_gather(
    const int* __restrict__ ssrc, const int* __restrict__ row_start,
    const float* __restrict__ Q, const float* __restrict__ K,
    const float* __restrict__ V, float* __restrict__ out, int n)
{
    int wid  = (blockIdx.x * blockDim.x + threadIdx.x) >> 6;   // node id
    if (wid >= n) return;
    const int lane = threadIdx.x & 63;

    const float2* Q2 = (const float2*)Q;
    const float2* V2 = (const float2*)V;
    const float2  kd = ((const float2*)K)[(size_t)wid * 64 + lane];

    const int e0 = row_start[wid];
    const int e1 = row_start[wid + 1];

    float accx = 0.f, accy = 0.f, dsum = 0.f;

    int i = e0;
    for (; i + 1 < e1; i += 2) {
        int sa = ssrc[i];
        int sb = ssrc[i + 1];
        float2 qa = Q2[(size_t)sa * 64 + lane];
        float2 va = V2[(size_t)sa * 64 + lane];
        float2 qb = Q2[(size_t)sb * 64 + lane];
        float2 vb = V2[(size_t)sb * 64 + lane];

        float pa = qa.x * kd.x + qa.y * kd.y;
        float pb = qb.x * kd.x + qb.y * kd.y;
#pragma unroll
        for (int off = 1; off < 16; off <<= 1) {
            pa += __shfl_xor(pa, off, 16);
            pb += __shfl_xor(pb, off, 16);
        }
        float ea = __expf(pa > 0.f ? pa : NEG_SLOPE * pa);
        float eb = __expf(pb > 0.f ? pb : NEG_SLOPE * pb);
        dsum += ea + eb;
        accx = fmaf(ea, va.x, accx); accx = fmaf(eb, vb.x, accx);
        accy = fmaf(ea, va.y, accy); accy = fmaf(eb, vb.y, accy);
    }
    if (i < e1) {
        int sa = ssrc[i];
        float2 qa = Q2[(size_t)sa * 64 + lane];
        float2 va = V2[(size_t)sa * 64 + lane];
        float pa = qa.x * kd.x + qa.y * kd.y;
#pragma unroll
        for (int off = 1; off < 16; off <<= 1) pa += __shfl_xor(pa, off, 16);
        float ea = __expf(pa > 0.f ? pa : NEG_SLOPE * pa);
        dsum += ea;
        accx = fmaf(ea, va.x, accx);
        accy = fmaf(ea, va.y, accy);
    }

    float inv = 1.f / fmaxf(dsum, 1e-9f);
    float2 o; o.x = accx * inv; o.y = accy * inv;
    ((float2*)out)[(size_t)wid * 64 + lane] = o;
}

extern "C" void kernel_launch(void* const* d_in, const int* in_sizes, int n_in,
                              void* d_out, int out_size, void* d_ws, size_t ws_size,
                              hipStream_t stream) {
    const float* h   = (const float*)d_in[0];
    const int*   src = (const int*)d_in[1];
    const int*   dst = (const int*)d_in[2];
    const float* Wq  = (const float*)d_in[3];
    const float* Wk  = (const float*)d_in[4];
    const float* Wv  = (const float*)d_in[5];
    float* out = (float*)d_out;

    const int n  = in_sizes[0] / IN_DIM;   // 50000
    const int ne = in_sizes[1];            // 1.6M
    const int nb = (n + 255) / 256;        // scan blocks (<=256)

    // workspace layout
    float* Q        = (float*)d_ws;
    float* K        = Q + (size_t)n * OUTC;
    float* V        = K + (size_t)n * OUTC;
    int*   count    = (int*)(V + (size_t)n * OUTC);
    int*   row_start= count + n;           // n+1 entries
    int*   cursor   = row_start + (n + 1);
    int*   bsum     = cursor + n;
    int*   ssrc     = bsum + 256;

    hipMemsetAsync(count, 0, (size_t)n * sizeof(int), stream);

    gat_proj<<<(n + 31) / 32, 128, 0, stream>>>(h, Wq, Wk, Wv, Q, K, V, n);

    int eblk = (ne + 255) / 256;
    gat_hist<<<eblk, 256, 0, stream>>>(dst, count, ne);
    gat_bsum<<<nb, 256, 0, stream>>>(count, bsum, n);
    gat_scan_bsum<<<1, 256, 0, stream>>>(bsum, nb);
    gat_scan_final<<<nb, 256, 0, stream>>>(count, bsum, row_start, cursor, n);
    gat_scatter<<<eblk, 256, 0, stream>>>(src, dst, cursor, ssrc, ne);

    int gblk = (n * 64 + 255) / 256;       // one wave64 per node
    gat_gather<<<gblk, 256, 0, stream>>>(ssrc, row_start, Q, K, V, out, n);
}

// Round 3
// 465.561 us; speedup vs baseline: 1.8304x; 1.1225x over previous
//
#include <hip/hip_runtime.h>

#define IN_DIM 128
#define HID 32
#define HEADS 4
#define OUTC (HEADS*HID)   // 128
#define NEG_SLOPE 0.2f

__device__ __forceinline__ float bf2f(unsigned short u) {
    return __uint_as_float(((unsigned)u) << 16);
}
__device__ __forceinline__ unsigned short f2bf(float f) {
    unsigned x = __float_as_uint(f);
    unsigned r = (x + 0x7fff + ((x >> 16) & 1)) >> 16;   // round-nearest-even
    return (unsigned short)r;
}

// ---------------------------------------------------------------------------
// K1: fused per-head projections Q,K,V = h @ W{q,k,v}   ([N,128] x [128,128])
// Q,K stored fp32; V stored bf16 (only feeds the value average).
// ---------------------------------------------------------------------------
__global__ __launch_bounds__(128) void gat_proj(
    const float* __restrict__ h,
    const float* __restrict__ Wq,
    const float* __restrict__ Wk,
    const float* __restrict__ Wv,
    float* __restrict__ Q, float* __restrict__ K,
    unsigned short* __restrict__ Vb,
    int n)
{
    __shared__ float hs[32][IN_DIM];
    const int c    = threadIdx.x;        // 0..127 output column (= head*32 + d)
    const int row0 = blockIdx.x * 32;

    for (int idx = threadIdx.x; idx < 32 * IN_DIM; idx += blockDim.x) {
        int r = idx >> 7, cc = idx & 127;
        int gr = row0 + r;
        hs[r][cc] = (gr < n) ? h[(size_t)gr * IN_DIM + cc] : 0.f;
    }
    __syncthreads();

    const int head = c >> 5, dcol = c & 31;
    const float* wqp = Wq + (size_t)head * IN_DIM * HID + dcol;
    const float* wkp = Wk + (size_t)head * IN_DIM * HID + dcol;
    const float* wvp = Wv + (size_t)head * IN_DIM * HID + dcol;

    float accq[32], acck[32], accv[32];
#pragma unroll
    for (int r = 0; r < 32; ++r) { accq[r] = 0.f; acck[r] = 0.f; accv[r] = 0.f; }

    for (int i = 0; i < IN_DIM; ++i) {
        float wq = wqp[(size_t)i * HID];
        float wk = wkp[(size_t)i * HID];
        float wv = wvp[(size_t)i * HID];
#pragma unroll
        for (int r = 0; r < 32; ++r) {
            float hv = hs[r][i];
            accq[r] = fmaf(hv, wq, accq[r]);
            acck[r] = fmaf(hv, wk, acck[r]);
            accv[r] = fmaf(hv, wv, accv[r]);
        }
    }

#pragma unroll
    for (int r = 0; r < 32; ++r) {
        int gr = row0 + r;
        if (gr < n) {
            size_t o = (size_t)gr * OUTC + c;
            Q[o]  = accq[r];
            K[o]  = acck[r];
            Vb[o] = f2bf(accv[r]);
        }
    }
}

// ---------------------------------------------------------------------------
// CSR build: histogram -> hierarchical exclusive scan -> scatter (int4)
// ---------------------------------------------------------------------------
__global__ __launch_bounds__(256) void gat_hist(
    const int* __restrict__ dst, int* __restrict__ count, int ne)
{
    int t  = blockIdx.x * blockDim.x + threadIdx.x;
    int np = ne >> 2;
    if (t < np) {
        int4 d = ((const int4*)dst)[t];
        atomicAdd(&count[d.x], 1);
        atomicAdd(&count[d.y], 1);
        atomicAdd(&count[d.z], 1);
        atomicAdd(&count[d.w], 1);
    } else if (t == np) {
        for (int e = np * 4; e < ne; ++e) atomicAdd(&count[dst[e]], 1);
    }
}

__global__ __launch_bounds__(256) void gat_bsum(
    const int* __restrict__ count, int* __restrict__ bsum, int n)
{
    __shared__ int ws[4];
    int i = blockIdx.x * 256 + threadIdx.x;
    int v = (i < n) ? count[i] : 0;
#pragma unroll
    for (int off = 32; off >= 1; off >>= 1) v += __shfl_down(v, off, 64);
    if ((threadIdx.x & 63) == 0) ws[threadIdx.x >> 6] = v;
    __syncthreads();
    if (threadIdx.x == 0) bsum[blockIdx.x] = ws[0] + ws[1] + ws[2] + ws[3];
}

__global__ __launch_bounds__(256) void gat_scan_bsum(int* bsum, int nb)
{
    __shared__ int s[256];
    int t = threadIdx.x;
    int v = (t < nb) ? bsum[t] : 0;
    s[t] = v; __syncthreads();
    for (int off = 1; off < 256; off <<= 1) {
        int u = (t >= off) ? s[t - off] : 0;
        __syncthreads();
        s[t] += u;
        __syncthreads();
    }
    if (t < nb) bsum[t] = s[t] - v;   // exclusive
}

__global__ __launch_bounds__(256) void gat_scan_final(
    const int* __restrict__ count, const int* __restrict__ bsum,
    int* __restrict__ row_start, int* __restrict__ cursor, int n)
{
    __shared__ int s[256];
    int t = threadIdx.x;
    int i = blockIdx.x * 256 + t;
    int v = (i < n) ? count[i] : 0;
    s[t] = v; __syncthreads();
    for (int off = 1; off < 256; off <<= 1) {
        int u = (t >= off) ? s[t - off] : 0;
        __syncthreads();
        s[t] += u;
        __syncthreads();
    }
    int excl = s[t] - v + bsum[blockIdx.x];
    if (i < n) { row_start[i] = excl; cursor[i] = excl; }
    if (i == n - 1) row_start[n] = excl + v;
}

__global__ __launch_bounds__(256) void gat_scatter(
    const int* __restrict__ src, const int* __restrict__ dst,
    int* __restrict__ cursor, int* __restrict__ ssrc, int ne)
{
    int t  = blockIdx.x * blockDim.x + threadIdx.x;
    int np = ne >> 2;
    if (t < np) {
        int4 s = ((const int4*)src)[t];
        int4 d = ((const int4*)dst)[t];
        ssrc[atomicAdd(&cursor[d.x], 1)] = s.x;
        ssrc[atomicAdd(&cursor[d.y], 1)] = s.y;
        ssrc[atomicAdd(&cursor[d.z], 1)] = s.z;
        ssrc[atomicAdd(&cursor[d.w], 1)] = s.w;
    } else if (t == np) {
        for (int e = np * 4; e < ne; ++e)
            ssrc[atomicAdd(&cursor[dst[e]], 1)] = src[e];
    }
}

// ---------------------------------------------------------------------------
// K2: gather — one wave64 per dst node; two 32-lane groups each own alternate
// incoming edges, unroll 2 per group => 4 edges in flight per wave-iter.
// Lane layout: l32 = lane&31 owns cols 4*l32..4*l32+3 (head = l32>>3).
// Q rows read as float4 (fp32), V rows as ushort4 (bf16). k[dst] in regs.
// Head dot reduced over 8 lanes (3 shfl stages). No atomics.
// ---------------------------------------------------------------------------
__global__ __launch_bounds__(256) void gat_gather(
    const int* __restrict__ ssrc, const int* __restrict__ row_start,
    const float* __restrict__ Q, const float* __restrict__ K,
    const unsigned short* __restrict__ Vb,
    float* __restrict__ out, int n)
{
    int wid = (blockIdx.x * blockDim.x + threadIdx.x) >> 6;   // node id
    if (wid >= n) return;
    const int lane = threadIdx.x & 63;
    const int l32  = lane & 31;
    const int g    = lane >> 5;

    const float4*  Q4 = (const float4*)Q;
    const float4*  K4 = (const float4*)K;
    const ushort4* V4 = (const ushort4*)Vb;

    const float4 kd = K4[(size_t)wid * 32 + l32];

    const int e0 = row_start[wid];
    const int e1 = row_start[wid + 1];

    float4 acc = make_float4(0.f, 0.f, 0.f, 0.f);
    float  dsum = 0.f;

    int j = e0 + g;
    for (; j + 2 < e1; j += 4) {
        const int sa = ssrc[j];
        const int sb = ssrc[j + 2];
        float4  qa = Q4[(size_t)sa * 32 + l32];
        ushort4 ua = V4[(size_t)sa * 32 + l32];
        float4  qb = Q4[(size_t)sb * 32 + l32];
        ushort4 ub = V4[(size_t)sb * 32 + l32];

        float pa = qa.x * kd.x + qa.y * kd.y + qa.z * kd.z + qa.w * kd.w;
        float pb = qb.x * kd.x + qb.y * kd.y + qb.z * kd.z + qb.w * kd.w;
#pragma unroll
        for (int off = 1; off < 8; off <<= 1) {
            pa += __shfl_xor(pa, off, 8);
            pb += __shfl_xor(pb, off, 8);
        }
        float ea = __expf(pa > 0.f ? pa : NEG_SLOPE * pa);
        float eb = __expf(pb > 0.f ? pb : NEG_SLOPE * pb);
        dsum += ea + eb;
        acc.x = fmaf(ea, bf2f(ua.x), acc.x);
        acc.y = fmaf(ea, bf2f(ua.y), acc.y);
        acc.z = fmaf(ea, bf2f(ua.z), acc.z);
        acc.w = fmaf(ea, bf2f(ua.w), acc.w);
        acc.x = fmaf(eb, bf2f(ub.x), acc.x);
        acc.y = fmaf(eb, bf2f(ub.y), acc.y);
        acc.z = fmaf(eb, bf2f(ub.z), acc.z);
        acc.w = fmaf(eb, bf2f(ub.w), acc.w);
    }
    if (j < e1) {
        const int sa = ssrc[j];
        float4  qa = Q4[(size_t)sa * 32 + l32];
        ushort4 ua = V4[(size_t)sa * 32 + l32];
        float pa = qa.x * kd.x + qa.y * kd.y + qa.z * kd.z + qa.w * kd.w;
#pragma unroll
        for (int off = 1; off < 8; off <<= 1) pa += __shfl_xor(pa, off, 8);
        float ea = __expf(pa > 0.f ? pa : NEG_SLOPE * pa);
        dsum += ea;
        acc.x = fmaf(ea, bf2f(ua.x), acc.x);
        acc.y = fmaf(ea, bf2f(ua.y), acc.y);
        acc.z = fmaf(ea, bf2f(ua.z), acc.z);
        acc.w = fmaf(ea, bf2f(ua.w), acc.w);
    }

    // combine the two 32-lane halves (same column set, disjoint edge subsets)
    acc.x += __shfl_xor(acc.x, 32, 64);
    acc.y += __shfl_xor(acc.y, 32, 64);
    acc.z += __shfl_xor(acc.z, 32, 64);
    acc.w += __shfl_xor(acc.w, 32, 64);
    dsum  += __shfl_xor(dsum, 32, 64);

    if (g == 0) {
        float inv = 1.f / fmaxf(dsum, 1e-9f);
        float4 o; o.x = acc.x*inv; o.y = acc.y*inv; o.z = acc.z*inv; o.w = acc.w*inv;
        ((float4*)out)[(size_t)wid * 32 + l32] = o;
    }
}

extern "C" void kernel_launch(void* const* d_in, const int* in_sizes, int n_in,
                              void* d_out, int out_size, void* d_ws, size_t ws_size,
                              hipStream_t stream) {
    const float* h   = (const float*)d_in[0];
    const int*   src = (const int*)d_in[1];
    const int*   dst = (const int*)d_in[2];
    const float* Wq  = (const float*)d_in[3];
    const float* Wk  = (const float*)d_in[4];
    const float* Wv  = (const float*)d_in[5];
    float* out = (float*)d_out;

    const int n  = in_sizes[0] / IN_DIM;   // 50000
    const int ne = in_sizes[1];            // 1.6M
    const int nb = (n + 255) / 256;        // scan blocks (<=256)

    // workspace layout
    float*          Q  = (float*)d_ws;
    float*          K  = Q + (size_t)n * OUTC;
    unsigned short* Vb = (unsigned short*)(K + (size_t)n * OUTC);
    int*   count     = (int*)(Vb + (size_t)n * OUTC);
    int*   row_start = count + n;          // n+1 entries
    int*   cursor    = row_start + (n + 1);
    int*   bsum      = cursor + n;
    int*   ssrc      = bsum + 256;

    hipMemsetAsync(count, 0, (size_t)n * sizeof(int), stream);

    gat_proj<<<(n + 31) / 32, 128, 0, stream>>>(h, Wq, Wk, Wv, Q, K, Vb, n);

    int np   = ne / 4;
    int eblk = (np + 1 + 255) / 256;
    gat_hist<<<eblk, 256, 0, stream>>>(dst, count, ne);
    gat_bsum<<<nb, 256, 0, stream>>>(count, bsum, n);
    gat_scan_bsum<<<1, 256, 0, stream>>>(bsum, nb);
    gat_scan_final<<<nb, 256, 0, stream>>>(count, bsum, row_start, cursor, n);
    gat_scatter<<<eblk, 256, 0, stream>>>(src, dst, cursor, ssrc, ne);

    int gblk = (n * 64 + 255) / 256;       // one wave64 per node
    gat_gather<<<gblk, 256, 0, stream>>>(ssrc, row_start, Q, K, Vb, out, n);
}

// Round 5
// 338.902 us; speedup vs baseline: 2.5144x; 1.3737x over previous
//
#include <hip/hip_runtime.h>
#include <hip/hip_fp16.h>

#define IN_DIM 128
#define HID 32
#define HEADS 4
#define OUTC (HEADS*HID)   // 128
#define NEG_SLOPE 0.2f
#define PAD 128            // max in-degree slots (Poisson(32): P(>128) ~ 1e-25)

__device__ __forceinline__ unsigned short f2h(float f) {
    return __half_as_ushort(__float2half_rn(f));
}
__device__ __forceinline__ float2 h2f2(unsigned u) {
    __half2 h = *reinterpret_cast<__half2*>(&u);
    return __half22float2(h);
}

// dot of fp16x4 q (packed in w.x,w.y) with fp32x4 kd
__device__ __forceinline__ float qdot(const uint4& qv, const float4& kd) {
    float2 a = h2f2(qv.x);
    float2 b = h2f2(qv.y);
    return a.x * kd.x + a.y * kd.y + b.x * kd.z + b.y * kd.w;
}
// acc += e * v (fp16x4 packed in w.z,w.w)
__device__ __forceinline__ void vacc(const uint4& qv, float e, float4& acc) {
    float2 a = h2f2(qv.z);
    float2 b = h2f2(qv.w);
    acc.x = fmaf(e, a.x, acc.x);
    acc.y = fmaf(e, a.y, acc.y);
    acc.z = fmaf(e, b.x, acc.z);
    acc.w = fmaf(e, b.y, acc.w);
}

// ---------------------------------------------------------------------------
// K1: fused projections. K stored fp32 [N][128]; Q,V stored fp16 interleaved:
// QV row = 512B: lane group (c>>2) holds {q[4g..4g+3], v[4g..4g+3]} as 8 ushorts.
// Gather lane l reads uint4 -> .xy = q fp16x4, .zw = v fp16x4.
// ---------------------------------------------------------------------------
__global__ __launch_bounds__(128) void gat_proj(
    const float* __restrict__ h,
    const float* __restrict__ Wq,
    const float* __restrict__ Wk,
    const float* __restrict__ Wv,
    float* __restrict__ K,
    unsigned short* __restrict__ QV,
    int n)
{
    __shared__ float hs[32][IN_DIM];
    const int c    = threadIdx.x;        // 0..127 output column (= head*32 + d)
    const int row0 = blockIdx.x * 32;

    for (int idx = threadIdx.x; idx < 32 * IN_DIM; idx += blockDim.x) {
        int r = idx >> 7, cc = idx & 127;
        int gr = row0 + r;
        hs[r][cc] = (gr < n) ? h[(size_t)gr * IN_DIM + cc] : 0.f;
    }
    __syncthreads();

    const int head = c >> 5, dcol = c & 31;
    const float* wqp = Wq + (size_t)head * IN_DIM * HID + dcol;
    const float* wkp = Wk + (size_t)head * IN_DIM * HID + dcol;
    const float* wvp = Wv + (size_t)head * IN_DIM * HID + dcol;

    float accq[32], acck[32], accv[32];
#pragma unroll
    for (int r = 0; r < 32; ++r) { accq[r] = 0.f; acck[r] = 0.f; accv[r] = 0.f; }

    for (int i = 0; i < IN_DIM; ++i) {
        float wq = wqp[(size_t)i * HID];
        float wk = wkp[(size_t)i * HID];
        float wv = wvp[(size_t)i * HID];
#pragma unroll
        for (int r = 0; r < 32; ++r) {
            float hv = hs[r][i];
            accq[r] = fmaf(hv, wq, accq[r]);
            acck[r] = fmaf(hv, wk, acck[r]);
            accv[r] = fmaf(hv, wv, accv[r]);
        }
    }

    const int qoff = (c >> 2) * 8 + (c & 3);   // ushort index within 256-ushort row
#pragma unroll
    for (int r = 0; r < 32; ++r) {
        int gr = row0 + r;
        if (gr < n) {
            K[(size_t)gr * OUTC + c] = acck[r];
            size_t base = (size_t)gr * 256;
            QV[base + qoff]     = f2h(accq[r]);
            QV[base + qoff + 4] = f2h(accv[r]);
        }
    }
}

// ---------------------------------------------------------------------------
// K2: padded-CSR scatter. pos = cnt[d]++; slots[d*PAD+pos] = src.
// ---------------------------------------------------------------------------
__global__ __launch_bounds__(256) void gat_scatter(
    const int* __restrict__ src, const int* __restrict__ dst,
    int* __restrict__ cnt, int* __restrict__ slots, int ne)
{
    int t  = blockIdx.x * blockDim.x + threadIdx.x;
    int np = ne >> 2;
    if (t < np) {
        int4 s = ((const int4*)src)[t];
        int4 d = ((const int4*)dst)[t];
        int p0 = atomicAdd(&cnt[d.x], 1);
        int p1 = atomicAdd(&cnt[d.y], 1);
        int p2 = atomicAdd(&cnt[d.z], 1);
        int p3 = atomicAdd(&cnt[d.w], 1);
        if (p0 < PAD) slots[(size_t)d.x * PAD + p0] = s.x;
        if (p1 < PAD) slots[(size_t)d.y * PAD + p1] = s.y;
        if (p2 < PAD) slots[(size_t)d.z * PAD + p2] = s.z;
        if (p3 < PAD) slots[(size_t)d.w * PAD + p3] = s.w;
    } else if (t == np) {
        for (int e = np * 4; e < ne; ++e) {
            int d = dst[e];
            int p = atomicAdd(&cnt[d], 1);
            if (p < PAD) slots[(size_t)d * PAD + p] = src[e];
        }
    }
}

// ---------------------------------------------------------------------------
// K3: gather — one wave64 per dst node; two 32-lane groups split the edge
// list in contiguous halves; unroll 4 => 8 x 16B loads in flight per wave.
// Per edge per lane: ONE uint4 (q fp16x4 | v fp16x4). k[dst] fp32 in regs.
// Head dot reduced over 8 lanes (3 shfl stages). No atomics.
// ---------------------------------------------------------------------------
__global__ __launch_bounds__(256) void gat_gather(
    const int* __restrict__ slots, const int* __restrict__ cnt,
    const uint4* __restrict__ QV, const float4* __restrict__ K4,
    float* __restrict__ out, int n)
{
    int wid = (blockIdx.x * blockDim.x + threadIdx.x) >> 6;   // node id
    if (wid >= n) return;
    const int lane = threadIdx.x & 63;
    const int l32  = lane & 31;
    const int g    = lane >> 5;

    const float4 kd = K4[(size_t)wid * 32 + l32];

    int deg = cnt[wid];
    if (deg > PAD) deg = PAD;
    const int* row = slots + (size_t)wid * PAD;

    const int half0 = (deg + 1) >> 1;
    const int jb = g ? half0 : 0;
    const int je = g ? deg   : half0;

    float4 acc = make_float4(0.f, 0.f, 0.f, 0.f);
    float  dsum = 0.f;

    int j = jb;
    for (; j + 3 < je; j += 4) {
        int s0 = row[j], s1 = row[j + 1], s2 = row[j + 2], s3 = row[j + 3];
        uint4 w0 = QV[(size_t)s0 * 32 + l32];
        uint4 w1 = QV[(size_t)s1 * 32 + l32];
        uint4 w2 = QV[(size_t)s2 * 32 + l32];
        uint4 w3 = QV[(size_t)s3 * 32 + l32];

        float p0 = qdot(w0, kd), p1 = qdot(w1, kd);
        float p2 = qdot(w2, kd), p3 = qdot(w3, kd);
#pragma unroll
        for (int off = 1; off < 8; off <<= 1) {
            p0 += __shfl_xor(p0, off, 8);
            p1 += __shfl_xor(p1, off, 8);
            p2 += __shfl_xor(p2, off, 8);
            p3 += __shfl_xor(p3, off, 8);
        }
        float e0 = __expf(p0 > 0.f ? p0 : NEG_SLOPE * p0);
        float e1 = __expf(p1 > 0.f ? p1 : NEG_SLOPE * p1);
        float e2 = __expf(p2 > 0.f ? p2 : NEG_SLOPE * p2);
        float e3 = __expf(p3 > 0.f ? p3 : NEG_SLOPE * p3);
        dsum += (e0 + e1) + (e2 + e3);
        vacc(w0, e0, acc); vacc(w1, e1, acc);
        vacc(w2, e2, acc); vacc(w3, e3, acc);
    }
    for (; j < je; ++j) {
        int s0 = row[j];
        uint4 w0 = QV[(size_t)s0 * 32 + l32];
        float p0 = qdot(w0, kd);
#pragma unroll
        for (int off = 1; off < 8; off <<= 1) p0 += __shfl_xor(p0, off, 8);
        float e0 = __expf(p0 > 0.f ? p0 : NEG_SLOPE * p0);
        dsum += e0;
        vacc(w0, e0, acc);
    }

    // combine the two 32-lane halves (same columns, disjoint edge subsets)
    acc.x += __shfl_xor(acc.x, 32, 64);
    acc.y += __shfl_xor(acc.y, 32, 64);
    acc.z += __shfl_xor(acc.z, 32, 64);
    acc.w += __shfl_xor(acc.w, 32, 64);
    dsum  += __shfl_xor(dsum, 32, 64);

    if (g == 0) {
        float inv = 1.f / fmaxf(dsum, 1e-9f);
        float4 o; o.x = acc.x*inv; o.y = acc.y*inv; o.z = acc.z*inv; o.w = acc.w*inv;
        ((float4*)out)[(size_t)wid * 32 + l32] = o;
    }
}

extern "C" void kernel_launch(void* const* d_in, const int* in_sizes, int n_in,
                              void* d_out, int out_size, void* d_ws, size_t ws_size,
                              hipStream_t stream) {
    const float* h   = (const float*)d_in[0];
    const int*   src = (const int*)d_in[1];
    const int*   dst = (const int*)d_in[2];
    const float* Wq  = (const float*)d_in[3];
    const float* Wk  = (const float*)d_in[4];
    const float* Wv  = (const float*)d_in[5];
    float* out = (float*)d_out;

    const int n  = in_sizes[0] / IN_DIM;   // 50000
    const int ne = in_sizes[1];            // 1.6M

    // workspace: K fp32 | QV fp16 | cnt | slots   (~77 MB)
    float*          K     = (float*)d_ws;
    unsigned short* QV    = (unsigned short*)(K + (size_t)n * OUTC);
    int*            cnt   = (int*)(QV + (size_t)n * 256);
    int*            slots = cnt + n;

    hipMemsetAsync(cnt, 0, (size_t)n * sizeof(int), stream);

    gat_proj<<<(n + 31) / 32, 128, 0, stream>>>(h, Wq, Wk, Wv, K, QV, n);

    int np = ne / 4;
    gat_scatter<<<(np + 1 + 255) / 256, 256, 0, stream>>>(src, dst, cnt, slots, ne);

    int gblk = (n * 64 + 255) / 256;       // one wave64 per node
    gat_gather<<<gblk, 256, 0, stream>>>(slots, cnt, (const uint4*)QV,
                                         (const float4*)K, out, n);
}

// Round 6
// 236.529 us; speedup vs baseline: 3.6027x; 1.4328x over previous
//
#include <hip/hip_runtime.h>
#include <hip/hip_fp16.h>

#define IN_DIM 128
#define HID 32
#define HEADS 4
#define OUTC (HEADS*HID)   // 128
#define NEG_SLOPE 0.2f
#define PAD 96             // max in-degree slots (Poisson(32): P(>96) ~ 4e-20)
#define BSHIFT 7
#define BNODES 128         // nodes per bucket
#define BCAP 6144          // edges per bucket region (avg 4096, +32 sigma)
#define MAXBUCK 512

__device__ __forceinline__ unsigned short f2h(float f) {
    return __half_as_ushort(__float2half_rn(f));
}
__device__ __forceinline__ float2 h2f2(unsigned u) {
    __half2 h = *reinterpret_cast<__half2*>(&u);
    return __half22float2(h);
}

// dot of fp16x4 q (packed in qv.x,qv.y) with fp32x4 kd
__device__ __forceinline__ float qdot(const uint4& qv, const float4& kd) {
    float2 a = h2f2(qv.x);
    float2 b = h2f2(qv.y);
    return a.x * kd.x + a.y * kd.y + b.x * kd.z + b.y * kd.w;
}
// acc += e * v (fp16x4 packed in qv.z,qv.w)
__device__ __forceinline__ void vacc(const uint4& qv, float e, float4& acc) {
    float2 a = h2f2(qv.z);
    float2 b = h2f2(qv.w);
    acc.x = fmaf(e, a.x, acc.x);
    acc.y = fmaf(e, a.y, acc.y);
    acc.z = fmaf(e, b.x, acc.z);
    acc.w = fmaf(e, b.y, acc.w);
}

// ---------------------------------------------------------------------------
// K1: fused projections. K stored fp32 [N][128]; Q,V stored fp16 interleaved:
// QV row = 512B: lane group (c>>2) holds {q[4g..4g+3], v[4g..4g+3]} as 8 ushorts.
// ---------------------------------------------------------------------------
__global__ __launch_bounds__(128) void gat_proj(
    const float* __restrict__ h,
    const float* __restrict__ Wq,
    const float* __restrict__ Wk,
    const float* __restrict__ Wv,
    float* __restrict__ K,
    unsigned short* __restrict__ QV,
    int n)
{
    __shared__ float hs[32][IN_DIM];
    const int c    = threadIdx.x;        // 0..127 output column (= head*32 + d)
    const int row0 = blockIdx.x * 32;

    for (int idx = threadIdx.x; idx < 32 * IN_DIM; idx += blockDim.x) {
        int r = idx >> 7, cc = idx & 127;
        int gr = row0 + r;
        hs[r][cc] = (gr < n) ? h[(size_t)gr * IN_DIM + cc] : 0.f;
    }
    __syncthreads();

    const int head = c >> 5, dcol = c & 31;
    const float* wqp = Wq + (size_t)head * IN_DIM * HID + dcol;
    const float* wkp = Wk + (size_t)head * IN_DIM * HID + dcol;
    const float* wvp = Wv + (size_t)head * IN_DIM * HID + dcol;

    float accq[32], acck[32], accv[32];
#pragma unroll
    for (int r = 0; r < 32; ++r) { accq[r] = 0.f; acck[r] = 0.f; accv[r] = 0.f; }

    for (int i = 0; i < IN_DIM; ++i) {
        float wq = wqp[(size_t)i * HID];
        float wk = wkp[(size_t)i * HID];
        float wv = wvp[(size_t)i * HID];
#pragma unroll
        for (int r = 0; r < 32; ++r) {
            float hv = hs[r][i];
            accq[r] = fmaf(hv, wq, accq[r]);
            acck[r] = fmaf(hv, wk, acck[r]);
            accv[r] = fmaf(hv, wv, accv[r]);
        }
    }

    const int qoff = (c >> 2) * 8 + (c & 3);   // ushort index within 256-ushort row
#pragma unroll
    for (int r = 0; r < 32; ++r) {
        int gr = row0 + r;
        if (gr < n) {
            K[(size_t)gr * OUTC + c] = acck[r];
            size_t base = (size_t)gr * 256;
            QV[base + qoff]     = f2h(accq[r]);
            QV[base + qoff + 4] = f2h(accv[r]);
        }
    }
}

// ---------------------------------------------------------------------------
// K2a: bin edges by bucket = dst>>7. LDS histogram -> one global atomicAdd
// per (block,bucket) -> packed record (src<<7 | dst&127) into bucket region.
// ---------------------------------------------------------------------------
__global__ __launch_bounds__(256) void gat_bin(
    const int* __restrict__ src, const int* __restrict__ dst,
    int* __restrict__ gcount, unsigned* __restrict__ pairs,
    int ne, int nbuck)
{
    __shared__ int hist[MAXBUCK];
    __shared__ int base[MAXBUCK];
    const int tid = threadIdx.x;
    for (int i = tid; i < nbuck; i += 256) hist[i] = 0;
    __syncthreads();

    const int ne4 = ne >> 2;
    const int4* s4 = (const int4*)src;
    const int4* d4 = (const int4*)dst;

    int4 sv[4], dv[4];
    int loc[16], bk[16];
    bool val[4];
#pragma unroll
    for (int k = 0; k < 4; ++k) {
        int idx = blockIdx.x * 1024 + k * 256 + tid;
        val[k] = idx < ne4;
        if (val[k]) { sv[k] = s4[idx]; dv[k] = d4[idx]; }
        else { sv[k] = make_int4(0,0,0,0); dv[k] = make_int4(0,0,0,0); }
    }
#pragma unroll
    for (int k = 0; k < 4; ++k) {
        int dd[4] = { dv[k].x, dv[k].y, dv[k].z, dv[k].w };
#pragma unroll
        for (int j = 0; j < 4; ++j) {
            int b = dd[j] >> BSHIFT;
            bk[k*4+j]  = b;
            loc[k*4+j] = val[k] ? atomicAdd(&hist[b], 1) : 0;
        }
    }
    __syncthreads();
    for (int i = tid; i < nbuck; i += 256)
        base[i] = hist[i] ? atomicAdd(&gcount[i], hist[i]) : 0;
    __syncthreads();
#pragma unroll
    for (int k = 0; k < 4; ++k) {
        if (!val[k]) continue;
        int ss[4] = { sv[k].x, sv[k].y, sv[k].z, sv[k].w };
        int dd[4] = { dv[k].x, dv[k].y, dv[k].z, dv[k].w };
#pragma unroll
        for (int j = 0; j < 4; ++j) {
            int b = bk[k*4+j];
            int p = base[b] + loc[k*4+j];
            if (p < BCAP)
                pairs[(size_t)b * BCAP + p] =
                    ((unsigned)ss[j] << BSHIFT) | (unsigned)(dd[j] & (BNODES-1));
        }
    }
    // tail (ne not a multiple of 4)
    if (blockIdx.x == 0 && tid == 0) {
        for (int e = ne4 * 4; e < ne; ++e) {
            int b = dst[e] >> BSHIFT;
            int p = atomicAdd(&gcount[b], 1);
            if (p < BCAP)
                pairs[(size_t)b * BCAP + p] =
                    ((unsigned)src[e] << BSHIFT) | (unsigned)(dst[e] & (BNODES-1));
        }
    }
}

// ---------------------------------------------------------------------------
// K2b: one block per bucket. All edges of a node live in its bucket ->
// LDS per-node counters (no global cnt atomics); slot writes stay in a
// 48KB L2-resident region per block.
// ---------------------------------------------------------------------------
__global__ __launch_bounds__(256) void gat_bscatter(
    const unsigned* __restrict__ pairs, const int* __restrict__ gcount,
    int* __restrict__ cnt, int* __restrict__ slots, int n)
{
    __shared__ int cl[BNODES];
    const int b   = blockIdx.x;
    const int tid = threadIdx.x;
    if (tid < BNODES) cl[tid] = 0;
    __syncthreads();

    int m = gcount[b];
    if (m > BCAP) m = BCAP;
    const unsigned* pb = pairs + (size_t)b * BCAP;
    for (int i = tid; i < m; i += 256) {
        unsigned p = pb[i];
        int dl  = p & (BNODES - 1);
        int s   = p >> BSHIFT;
        int pos = atomicAdd(&cl[dl], 1);
        if (pos < PAD) slots[((size_t)b * BNODES + dl) * PAD + pos] = s;
    }
    __syncthreads();
    int node = b * BNODES + tid;
    if (tid < BNODES && node < n) cnt[node] = cl[tid];
}

// ---------------------------------------------------------------------------
// K3: gather — one wave64 per dst node; two 32-lane groups split the edge
// list in contiguous halves; unroll 4 => 8 x 16B loads in flight per wave.
// Per edge per lane: ONE uint4 (q fp16x4 | v fp16x4). k[dst] fp32 in regs.
// ---------------------------------------------------------------------------
__global__ __launch_bounds__(256) void gat_gather(
    const int* __restrict__ slots, const int* __restrict__ cnt,
    const uint4* __restrict__ QV, const float4* __restrict__ K4,
    float* __restrict__ out, int n)
{
    int wid = (blockIdx.x * blockDim.x + threadIdx.x) >> 6;   // node id
    if (wid >= n) return;
    const int lane = threadIdx.x & 63;
    const int l32  = lane & 31;
    const int g    = lane >> 5;

    const float4 kd = K4[(size_t)wid * 32 + l32];

    int deg = cnt[wid];
    if (deg > PAD) deg = PAD;
    const int* row = slots + (size_t)wid * PAD;

    const int half0 = (deg + 1) >> 1;
    const int jb = g ? half0 : 0;
    const int je = g ? deg   : half0;

    float4 acc = make_float4(0.f, 0.f, 0.f, 0.f);
    float  dsum = 0.f;

    int j = jb;
    for (; j + 3 < je; j += 4) {
        int s0 = row[j], s1 = row[j + 1], s2 = row[j + 2], s3 = row[j + 3];
        uint4 w0 = QV[(size_t)s0 * 32 + l32];
        uint4 w1 = QV[(size_t)s1 * 32 + l32];
        uint4 w2 = QV[(size_t)s2 * 32 + l32];
        uint4 w3 = QV[(size_t)s3 * 32 + l32];

        float p0 = qdot(w0, kd), p1 = qdot(w1, kd);
        float p2 = qdot(w2, kd), p3 = qdot(w3, kd);
#pragma unroll
        for (int off = 1; off < 8; off <<= 1) {
            p0 += __shfl_xor(p0, off, 8);
            p1 += __shfl_xor(p1, off, 8);
            p2 += __shfl_xor(p2, off, 8);
            p3 += __shfl_xor(p3, off, 8);
        }
        float e0 = __expf(p0 > 0.f ? p0 : NEG_SLOPE * p0);
        float e1 = __expf(p1 > 0.f ? p1 : NEG_SLOPE * p1);
        float e2 = __expf(p2 > 0.f ? p2 : NEG_SLOPE * p2);
        float e3 = __expf(p3 > 0.f ? p3 : NEG_SLOPE * p3);
        dsum += (e0 + e1) + (e2 + e3);
        vacc(w0, e0, acc); vacc(w1, e1, acc);
        vacc(w2, e2, acc); vacc(w3, e3, acc);
    }
    for (; j < je; ++j) {
        int s0 = row[j];
        uint4 w0 = QV[(size_t)s0 * 32 + l32];
        float p0 = qdot(w0, kd);
#pragma unroll
        for (int off = 1; off < 8; off <<= 1) p0 += __shfl_xor(p0, off, 8);
        float e0 = __expf(p0 > 0.f ? p0 : NEG_SLOPE * p0);
        dsum += e0;
        vacc(w0, e0, acc);
    }

    // combine the two 32-lane halves (same columns, disjoint edge subsets)
    acc.x += __shfl_xor(acc.x, 32, 64);
    acc.y += __shfl_xor(acc.y, 32, 64);
    acc.z += __shfl_xor(acc.z, 32, 64);
    acc.w += __shfl_xor(acc.w, 32, 64);
    dsum  += __shfl_xor(dsum, 32, 64);

    if (g == 0) {
        float inv = 1.f / fmaxf(dsum, 1e-9f);
        float4 o; o.x = acc.x*inv; o.y = acc.y*inv; o.z = acc.z*inv; o.w = acc.w*inv;
        ((float4*)out)[(size_t)wid * 32 + l32] = o;
    }
}

extern "C" void kernel_launch(void* const* d_in, const int* in_sizes, int n_in,
                              void* d_out, int out_size, void* d_ws, size_t ws_size,
                              hipStream_t stream) {
    const float* h   = (const float*)d_in[0];
    const int*   src = (const int*)d_in[1];
    const int*   dst = (const int*)d_in[2];
    const float* Wq  = (const float*)d_in[3];
    const float* Wk  = (const float*)d_in[4];
    const float* Wv  = (const float*)d_in[5];
    float* out = (float*)d_out;

    const int n     = in_sizes[0] / IN_DIM;   // 50000
    const int ne    = in_sizes[1];            // 1.6M
    const int nbuck = (n + BNODES - 1) >> BSHIFT;

    // workspace: K f32 | QV f16 | cnt | slots | gcount | pairs  (~80 MB)
    float*          K      = (float*)d_ws;
    unsigned short* QV     = (unsigned short*)(K + (size_t)n * OUTC);
    int*            cnt    = (int*)(QV + (size_t)n * 256);
    int*            slots  = cnt + n;
    int*            gcount = slots + (size_t)n * PAD;
    unsigned*       pairs  = (unsigned*)(gcount + MAXBUCK);

    hipMemsetAsync(gcount, 0, MAXBUCK * sizeof(int), stream);

    gat_proj<<<(n + 31) / 32, 128, 0, stream>>>(h, Wq, Wk, Wv, K, QV, n);

    int ne4 = ne >> 2;
    int binblk = (ne4 + 1023) / 1024;
    gat_bin<<<binblk, 256, 0, stream>>>(src, dst, gcount, pairs, ne, nbuck);
    gat_bscatter<<<nbuck, 256, 0, stream>>>(pairs, gcount, cnt, slots, n);

    int gblk = (n * 64 + 255) / 256;       // one wave64 per node
    gat_gather<<<gblk, 256, 0, stream>>>(slots, cnt, (const uint4*)QV,
                                         (const float4*)K, out, n);
}

// Round 7
// 187.970 us; speedup vs baseline: 4.5334x; 1.2583x over previous
//
#include <hip/hip_runtime.h>
#include <hip/hip_fp16.h>

#define IN_DIM 128
#define HID 32
#define HEADS 4
#define OUTC (HEADS*HID)   // 128
#define NEG_SLOPE 0.2f
#define PAD 96             // max in-degree slots (Poisson(32): P(>96) ~ 4e-20)
#define BSHIFT 7
#define BNODES 128         // nodes per bucket
#define BCAP 6144          // edges per bucket region (avg 4096, +32 sigma)
#define MAXBUCK 512
#define NCOLS 384          // k(128) | q(128) | v(128)

typedef _Float16 f16x8 __attribute__((ext_vector_type(8)));
typedef float    f32x4 __attribute__((ext_vector_type(4)));

__device__ __forceinline__ unsigned short f2h(float f) {
    return __half_as_ushort(__float2half_rn(f));
}
__device__ __forceinline__ float2 h2f2(unsigned u) {
    __half2 h = *reinterpret_cast<__half2*>(&u);
    return __half22float2(h);
}
__device__ __forceinline__ float qdot(const uint4& qv, const float4& kd) {
    float2 a = h2f2(qv.x);
    float2 b = h2f2(qv.y);
    return a.x * kd.x + a.y * kd.y + b.x * kd.z + b.y * kd.w;
}
__device__ __forceinline__ void vacc(const uint4& qv, float e, float4& acc) {
    float2 a = h2f2(qv.z);
    float2 b = h2f2(qv.w);
    acc.x = fmaf(e, a.x, acc.x);
    acc.y = fmaf(e, a.y, acc.y);
    acc.z = fmaf(e, b.x, acc.z);
    acc.w = fmaf(e, b.y, acc.w);
}

// ---------------------------------------------------------------------------
// K0: W prep — Wt[c][k] fp16, c: 0..127 = Wk cols, 128..255 = Wq, 256..383 = Wv
// (B^T layout: fragment loads are 8 consecutive k per lane)
// ---------------------------------------------------------------------------
__global__ __launch_bounds__(256) void w_prep(
    const float* __restrict__ Wq, const float* __restrict__ Wk,
    const float* __restrict__ Wv, unsigned short* __restrict__ Wt)
{
    int idx = blockIdx.x * 256 + threadIdx.x;
    if (idx >= NCOLS * IN_DIM) return;
    int c = idx >> 7, k = idx & 127;
    int sel = c >> 7;              // 0:K 1:Q 2:V
    int cc  = c & 127;
    int head = cc >> 5, dcol = cc & 31;
    const float* W = (sel == 0) ? Wk : (sel == 1) ? Wq : Wv;
    Wt[idx] = f2h(W[(size_t)head * IN_DIM * HID + (size_t)k * HID + dcol]);
}

// ---------------------------------------------------------------------------
// K1: MFMA projections. [32 rows] x [K=128] x [N=384] per block (4 waves).
// A: h tile fp16 in LDS, XOR-swizzled (col ^= (row&7)<<3) to kill the
// 256B-row-stride bank conflict on ds_read_b128.
// Wave w covers cols [w*96, w*96+96) = 6 col-tiles; 2 row-tiles of 16.
// D layout (verified): col=lane&15, row=(lane>>4)*4+reg.
// ---------------------------------------------------------------------------
__global__ __launch_bounds__(256) void gat_proj_mfma(
    const float* __restrict__ h, const unsigned short* __restrict__ Wt,
    float* __restrict__ Ko, unsigned short* __restrict__ QV, int n)
{
    __shared__ unsigned short hsm[32 * IN_DIM];   // fp16 bits, 8KB
    const int tid  = threadIdx.x;
    const int row0 = blockIdx.x * 32;

    // stage h tile (fp32 -> fp16), swizzled
    for (int idx = tid; idx < 32 * 64; idx += 256) {
        int r  = idx >> 6;
        int c2 = idx & 63;            // float2 column
        int gr = row0 + r;
        float2 hv = (gr < n) ? ((const float2*)h)[(size_t)gr * 64 + c2]
                             : make_float2(0.f, 0.f);
        int col = c2 * 2;
        int sc  = col ^ ((r & 7) << 3);
        __half2 packed = __floats2half2_rn(hv.x, hv.y);
        *(unsigned*)&hsm[r * IN_DIM + sc] = *(unsigned*)&packed;
    }
    __syncthreads();

    const int w = tid >> 6;           // wave 0..3
    const int l = tid & 63;
    const int l15 = l & 15;
    const int kg  = l >> 4;           // 0..3
    const _Float16* Wt16 = (const _Float16*)Wt;

    f32x4 acc[2][6];
#pragma unroll
    for (int rt = 0; rt < 2; ++rt)
#pragma unroll
        for (int ct = 0; ct < 6; ++ct) acc[rt][ct] = (f32x4){0.f, 0.f, 0.f, 0.f};

#pragma unroll
    for (int s = 0; s < 4; ++s) {
        int scol = (s * 32 + kg * 8) ^ ((l & 7) << 3);
        f16x8 a0 = *(const f16x8*)&hsm[l15 * IN_DIM + scol];
        f16x8 a1 = *(const f16x8*)&hsm[(l15 + 16) * IN_DIM + scol];
#pragma unroll
        for (int ct = 0; ct < 6; ++ct) {
            int c = w * 96 + ct * 16 + l15;
            f16x8 b = *(const f16x8*)&Wt16[(size_t)c * IN_DIM + s * 32 + kg * 8];
            acc[0][ct] = __builtin_amdgcn_mfma_f32_16x16x32_f16(a0, b, acc[0][ct], 0, 0, 0);
            acc[1][ct] = __builtin_amdgcn_mfma_f32_16x16x32_f16(a1, b, acc[1][ct], 0, 0, 0);
        }
    }

#pragma unroll
    for (int rt = 0; rt < 2; ++rt) {
#pragma unroll
        for (int ct = 0; ct < 6; ++ct) {
            int cD = w * 96 + ct * 16 + l15;
#pragma unroll
            for (int r = 0; r < 4; ++r) {
                int node = row0 + rt * 16 + kg * 4 + r;
                if (node >= n) continue;
                float v = acc[rt][ct][r];
                if (cD < 128) {
                    Ko[(size_t)node * OUTC + cD] = v;
                } else if (cD < 256) {
                    int cq = cD - 128;
                    QV[(size_t)node * 256 + (cq >> 2) * 8 + (cq & 3)] = f2h(v);
                } else {
                    int cv = cD - 256;
                    QV[(size_t)node * 256 + (cv >> 2) * 8 + (cv & 3) + 4] = f2h(v);
                }
            }
        }
    }
}

// ---------------------------------------------------------------------------
// K2a: bin edges by bucket = dst>>7 (packed record src<<7 | dst&127).
// ---------------------------------------------------------------------------
__global__ __launch_bounds__(256) void gat_bin(
    const int* __restrict__ src, const int* __restrict__ dst,
    int* __restrict__ gcount, unsigned* __restrict__ pairs,
    int ne, int nbuck)
{
    __shared__ int hist[MAXBUCK];
    __shared__ int base[MAXBUCK];
    const int tid = threadIdx.x;
    for (int i = tid; i < nbuck; i += 256) hist[i] = 0;
    __syncthreads();

    const int ne4 = ne >> 2;
    const int4* s4 = (const int4*)src;
    const int4* d4 = (const int4*)dst;

    int4 sv[4], dv[4];
    int loc[16], bk[16];
    bool val[4];
#pragma unroll
    for (int k = 0; k < 4; ++k) {
        int idx = blockIdx.x * 1024 + k * 256 + tid;
        val[k] = idx < ne4;
        if (val[k]) { sv[k] = s4[idx]; dv[k] = d4[idx]; }
        else { sv[k] = make_int4(0,0,0,0); dv[k] = make_int4(0,0,0,0); }
    }
#pragma unroll
    for (int k = 0; k < 4; ++k) {
        int dd[4] = { dv[k].x, dv[k].y, dv[k].z, dv[k].w };
#pragma unroll
        for (int j = 0; j < 4; ++j) {
            int b = dd[j] >> BSHIFT;
            bk[k*4+j]  = b;
            loc[k*4+j] = val[k] ? atomicAdd(&hist[b], 1) : 0;
        }
    }
    __syncthreads();
    for (int i = tid; i < nbuck; i += 256)
        base[i] = hist[i] ? atomicAdd(&gcount[i], hist[i]) : 0;
    __syncthreads();
#pragma unroll
    for (int k = 0; k < 4; ++k) {
        if (!val[k]) continue;
        int ss[4] = { sv[k].x, sv[k].y, sv[k].z, sv[k].w };
        int dd[4] = { dv[k].x, dv[k].y, dv[k].z, dv[k].w };
#pragma unroll
        for (int j = 0; j < 4; ++j) {
            int b = bk[k*4+j];
            int p = base[b] + loc[k*4+j];
            if (p < BCAP)
                pairs[(size_t)b * BCAP + p] =
                    ((unsigned)ss[j] << BSHIFT) | (unsigned)(dd[j] & (BNODES-1));
        }
    }
    if (blockIdx.x == 0 && tid == 0) {
        for (int e = ne4 * 4; e < ne; ++e) {
            int b = dst[e] >> BSHIFT;
            int p = atomicAdd(&gcount[b], 1);
            if (p < BCAP)
                pairs[(size_t)b * BCAP + p] =
                    ((unsigned)src[e] << BSHIFT) | (unsigned)(dst[e] & (BNODES-1));
        }
    }
}

// ---------------------------------------------------------------------------
// K2b: per bucket: counting-sort records by coarse src-bin (src>>9) so each
// node's slot list is src-ascending -> concurrently-resident gather waves
// sweep src space in rough lockstep -> small active QV window -> L2 hits.
// Then append via LDS per-node cursors.
// ---------------------------------------------------------------------------
#define SBINS 128   // src>>9 for n=50000 -> 98 bins
__global__ __launch_bounds__(256) void gat_bscatter(
    const unsigned* __restrict__ pairs, const int* __restrict__ gcount,
    int* __restrict__ cnt, int* __restrict__ slots, int n)
{
    __shared__ unsigned buf[BCAP];     // 24KB
    __shared__ unsigned sorted[BCAP];  // 24KB
    __shared__ int cl[BNODES];
    __shared__ int bh[SBINS], bb[SBINS], bc[SBINS];
    const int b   = blockIdx.x;
    const int tid = threadIdx.x;
    if (tid < BNODES) cl[tid] = 0;
    if (tid < SBINS) bh[tid] = 0;
    __syncthreads();

    int m = gcount[b];
    if (m > BCAP) m = BCAP;
    const unsigned* pb = pairs + (size_t)b * BCAP;

    for (int i = tid; i < m; i += 256) {
        unsigned p = pb[i];
        buf[i] = p;
        atomicAdd(&bh[(p >> BSHIFT) >> 9], 1);
    }
    __syncthreads();

    // exclusive scan of bh (Hillis-Steele over SBINS)
    if (tid < SBINS) bb[tid] = bh[tid];
    __syncthreads();
    for (int off = 1; off < SBINS; off <<= 1) {
        int v = 0;
        if (tid < SBINS && tid >= off) v = bb[tid - off];
        __syncthreads();
        if (tid < SBINS) bb[tid] += v;
        __syncthreads();
    }
    if (tid < SBINS) { bb[tid] -= bh[tid]; bc[tid] = bb[tid]; }
    __syncthreads();

    for (int i = tid; i < m; i += 256) {
        unsigned p = buf[i];
        int pos = atomicAdd(&bc[(p >> BSHIFT) >> 9], 1);
        sorted[pos] = p;
    }
    __syncthreads();

    for (int i = tid; i < m; i += 256) {
        unsigned p = sorted[i];
        int dl  = p & (BNODES - 1);
        int s   = p >> BSHIFT;
        int pos = atomicAdd(&cl[dl], 1);
        if (pos < PAD) slots[((size_t)b * BNODES + dl) * PAD + pos] = s;
    }
    __syncthreads();
    int node = b * BNODES + tid;
    if (tid < BNODES && node < n) cnt[node] = cl[tid];
}

// ---------------------------------------------------------------------------
// K3: gather — one wave64 per dst node (unchanged from round 6).
// ---------------------------------------------------------------------------
__global__ __launch_bounds__(256) void gat_gather(
    const int* __restrict__ slots, const int* __restrict__ cnt,
    const uint4* __restrict__ QV, const float4* __restrict__ K4,
    float* __restrict__ out, int n)
{
    int wid = (blockIdx.x * blockDim.x + threadIdx.x) >> 6;   // node id
    if (wid >= n) return;
    const int lane = threadIdx.x & 63;
    const int l32  = lane & 31;
    const int g    = lane >> 5;

    const float4 kd = K4[(size_t)wid * 32 + l32];

    int deg = cnt[wid];
    if (deg > PAD) deg = PAD;
    const int* row = slots + (size_t)wid * PAD;

    const int half0 = (deg + 1) >> 1;
    const int jb = g ? half0 : 0;
    const int je = g ? deg   : half0;

    float4 acc = make_float4(0.f, 0.f, 0.f, 0.f);
    float  dsum = 0.f;

    int j = jb;
    for (; j + 3 < je; j += 4) {
        int s0 = row[j], s1 = row[j + 1], s2 = row[j + 2], s3 = row[j + 3];
        uint4 w0 = QV[(size_t)s0 * 32 + l32];
        uint4 w1 = QV[(size_t)s1 * 32 + l32];
        uint4 w2 = QV[(size_t)s2 * 32 + l32];
        uint4 w3 = QV[(size_t)s3 * 32 + l32];

        float p0 = qdot(w0, kd), p1 = qdot(w1, kd);
        float p2 = qdot(w2, kd), p3 = qdot(w3, kd);
#pragma unroll
        for (int off = 1; off < 8; off <<= 1) {
            p0 += __shfl_xor(p0, off, 8);
            p1 += __shfl_xor(p1, off, 8);
            p2 += __shfl_xor(p2, off, 8);
            p3 += __shfl_xor(p3, off, 8);
        }
        float e0 = __expf(p0 > 0.f ? p0 : NEG_SLOPE * p0);
        float e1 = __expf(p1 > 0.f ? p1 : NEG_SLOPE * p1);
        float e2 = __expf(p2 > 0.f ? p2 : NEG_SLOPE * p2);
        float e3 = __expf(p3 > 0.f ? p3 : NEG_SLOPE * p3);
        dsum += (e0 + e1) + (e2 + e3);
        vacc(w0, e0, acc); vacc(w1, e1, acc);
        vacc(w2, e2, acc); vacc(w3, e3, acc);
    }
    for (; j < je; ++j) {
        int s0 = row[j];
        uint4 w0 = QV[(size_t)s0 * 32 + l32];
        float p0 = qdot(w0, kd);
#pragma unroll
        for (int off = 1; off < 8; off <<= 1) p0 += __shfl_xor(p0, off, 8);
        float e0 = __expf(p0 > 0.f ? p0 : NEG_SLOPE * p0);
        dsum += e0;
        vacc(w0, e0, acc);
    }

    acc.x += __shfl_xor(acc.x, 32, 64);
    acc.y += __shfl_xor(acc.y, 32, 64);
    acc.z += __shfl_xor(acc.z, 32, 64);
    acc.w += __shfl_xor(acc.w, 32, 64);
    dsum  += __shfl_xor(dsum, 32, 64);

    if (g == 0) {
        float inv = 1.f / fmaxf(dsum, 1e-9f);
        float4 o; o.x = acc.x*inv; o.y = acc.y*inv; o.z = acc.z*inv; o.w = acc.w*inv;
        ((float4*)out)[(size_t)wid * 32 + l32] = o;
    }
}

extern "C" void kernel_launch(void* const* d_in, const int* in_sizes, int n_in,
                              void* d_out, int out_size, void* d_ws, size_t ws_size,
                              hipStream_t stream) {
    const float* h   = (const float*)d_in[0];
    const int*   src = (const int*)d_in[1];
    const int*   dst = (const int*)d_in[2];
    const float* Wq  = (const float*)d_in[3];
    const float* Wk  = (const float*)d_in[4];
    const float* Wv  = (const float*)d_in[5];
    float* out = (float*)d_out;

    const int n     = in_sizes[0] / IN_DIM;   // 50000
    const int ne    = in_sizes[1];            // 1.6M
    const int nbuck = (n + BNODES - 1) >> BSHIFT;

    // workspace: K f32 | QV f16 | cnt | slots | gcount | pairs | Wt  (~80.4 MB)
    float*          K      = (float*)d_ws;
    unsigned short* QV     = (unsigned short*)(K + (size_t)n * OUTC);
    int*            cnt    = (int*)(QV + (size_t)n * 256);
    int*            slots  = cnt + n;
    int*            gcount = slots + (size_t)n * PAD;
    unsigned*       pairs  = (unsigned*)(gcount + MAXBUCK);
    unsigned short* Wt     = (unsigned short*)(pairs + (size_t)MAXBUCK * BCAP);

    hipMemsetAsync(gcount, 0, MAXBUCK * sizeof(int), stream);

    w_prep<<<(NCOLS * IN_DIM + 255) / 256, 256, 0, stream>>>(Wq, Wk, Wv, Wt);
    gat_proj_mfma<<<(n + 31) / 32, 256, 0, stream>>>(h, Wt, K, QV, n);

    int ne4 = ne >> 2;
    int binblk = (ne4 + 1023) / 1024;
    gat_bin<<<binblk, 256, 0, stream>>>(src, dst, gcount, pairs, ne, nbuck);
    gat_bscatter<<<nbuck, 256, 0, stream>>>(pairs, gcount, cnt, slots, n);

    int gblk = (n * 64 + 255) / 256;       // one wave64 per node
    gat_gather<<<gblk, 256, 0, stream>>>(slots, cnt, (const uint4*)QV,
                                         (const float4*)K, out, n);
}

// Round 8
// 183.653 us; speedup vs baseline: 4.6400x; 1.0235x over previous
//
#include <hip/hip_runtime.h>
#include <hip/hip_fp16.h>

#define IN_DIM 128
#define HID 32
#define HEADS 4
#define OUTC (HEADS*HID)   // 128
#define NEG_SLOPE 0.2f
#define BSHIFT 7
#define BNODES 128         // nodes per bucket
#define BCAP 6144          // edges per bucket region (avg 4096, +32 sigma)
#define MAXBUCK 512
#define NCOLS 384          // k(128) | q(128) | v(128)
#define SUBN 16            // nodes per sub-block in fused kernel
#define SCAP 1024          // max edges per sub-block (mean 512, +22 sigma)

typedef _Float16 f16x8 __attribute__((ext_vector_type(8)));
typedef float    f32x4 __attribute__((ext_vector_type(4)));

__device__ __forceinline__ unsigned short f2h(float f) {
    return __half_as_ushort(__float2half_rn(f));
}
__device__ __forceinline__ float2 h2f2(unsigned u) {
    __half2 h = *reinterpret_cast<__half2*>(&u);
    return __half22float2(h);
}
__device__ __forceinline__ float qdot(const uint4& qv, const float4& kd) {
    float2 a = h2f2(qv.x);
    float2 b = h2f2(qv.y);
    return a.x * kd.x + a.y * kd.y + b.x * kd.z + b.y * kd.w;
}
__device__ __forceinline__ void vacc(const uint4& qv, float e, float4& acc) {
    float2 a = h2f2(qv.z);
    float2 b = h2f2(qv.w);
    acc.x = fmaf(e, a.x, acc.x);
    acc.y = fmaf(e, a.y, acc.y);
    acc.z = fmaf(e, b.x, acc.z);
    acc.w = fmaf(e, b.y, acc.w);
}

// ---------------------------------------------------------------------------
// K0: W prep (fp16 B^T layout) + zero gcount (kernel boundary = fence).
// ---------------------------------------------------------------------------
__global__ __launch_bounds__(256) void w_prep(
    const float* __restrict__ Wq, const float* __restrict__ Wk,
    const float* __restrict__ Wv, unsigned short* __restrict__ Wt,
    int* __restrict__ gcount)
{
    int idx = blockIdx.x * 256 + threadIdx.x;
    if (idx < MAXBUCK) gcount[idx] = 0;
    if (idx >= NCOLS * IN_DIM) return;
    int c = idx >> 7, k = idx & 127;
    int sel = c >> 7;              // 0:K 1:Q 2:V
    int cc  = c & 127;
    int head = cc >> 5, dcol = cc & 31;
    const float* W = (sel == 0) ? Wk : (sel == 1) ? Wq : Wv;
    Wt[idx] = f2h(W[(size_t)head * IN_DIM * HID + (size_t)k * HID + dcol]);
}

// ---------------------------------------------------------------------------
// K1: MFMA projections (unchanged from round 7, verified).
// ---------------------------------------------------------------------------
__global__ __launch_bounds__(256) void gat_proj_mfma(
    const float* __restrict__ h, const unsigned short* __restrict__ Wt,
    float* __restrict__ Ko, unsigned short* __restrict__ QV, int n)
{
    __shared__ unsigned short hsm[32 * IN_DIM];   // fp16 bits, 8KB
    const int tid  = threadIdx.x;
    const int row0 = blockIdx.x * 32;

    for (int idx = tid; idx < 32 * 64; idx += 256) {
        int r  = idx >> 6;
        int c2 = idx & 63;
        int gr = row0 + r;
        float2 hv = (gr < n) ? ((const float2*)h)[(size_t)gr * 64 + c2]
                             : make_float2(0.f, 0.f);
        int col = c2 * 2;
        int sc  = col ^ ((r & 7) << 3);
        __half2 packed = __floats2half2_rn(hv.x, hv.y);
        *(unsigned*)&hsm[r * IN_DIM + sc] = *(unsigned*)&packed;
    }
    __syncthreads();

    const int w = tid >> 6;
    const int l = tid & 63;
    const int l15 = l & 15;
    const int kg  = l >> 4;
    const _Float16* Wt16 = (const _Float16*)Wt;

    f32x4 acc[2][6];
#pragma unroll
    for (int rt = 0; rt < 2; ++rt)
#pragma unroll
        for (int ct = 0; ct < 6; ++ct) acc[rt][ct] = (f32x4){0.f, 0.f, 0.f, 0.f};

#pragma unroll
    for (int s = 0; s < 4; ++s) {
        int scol = (s * 32 + kg * 8) ^ ((l & 7) << 3);
        f16x8 a0 = *(const f16x8*)&hsm[l15 * IN_DIM + scol];
        f16x8 a1 = *(const f16x8*)&hsm[(l15 + 16) * IN_DIM + scol];
#pragma unroll
        for (int ct = 0; ct < 6; ++ct) {
            int c = w * 96 + ct * 16 + l15;
            f16x8 b = *(const f16x8*)&Wt16[(size_t)c * IN_DIM + s * 32 + kg * 8];
            acc[0][ct] = __builtin_amdgcn_mfma_f32_16x16x32_f16(a0, b, acc[0][ct], 0, 0, 0);
            acc[1][ct] = __builtin_amdgcn_mfma_f32_16x16x32_f16(a1, b, acc[1][ct], 0, 0, 0);
        }
    }

#pragma unroll
    for (int rt = 0; rt < 2; ++rt) {
#pragma unroll
        for (int ct = 0; ct < 6; ++ct) {
            int cD = w * 96 + ct * 16 + l15;
#pragma unroll
            for (int r = 0; r < 4; ++r) {
                int node = row0 + rt * 16 + kg * 4 + r;
                if (node >= n) continue;
                float v = acc[rt][ct][r];
                if (cD < 128) {
                    Ko[(size_t)node * OUTC + cD] = v;
                } else if (cD < 256) {
                    int cq = cD - 128;
                    QV[(size_t)node * 256 + (cq >> 2) * 8 + (cq & 3)] = f2h(v);
                } else {
                    int cv = cD - 256;
                    QV[(size_t)node * 256 + (cv >> 2) * 8 + (cv & 3) + 4] = f2h(v);
                }
            }
        }
    }
}

// ---------------------------------------------------------------------------
// K2: bin edges by bucket = dst>>7 (packed record src<<7 | dst&127).
// ---------------------------------------------------------------------------
__global__ __launch_bounds__(256) void gat_bin(
    const int* __restrict__ src, const int* __restrict__ dst,
    int* __restrict__ gcount, unsigned* __restrict__ pairs,
    int ne, int nbuck)
{
    __shared__ int hist[MAXBUCK];
    __shared__ int base[MAXBUCK];
    const int tid = threadIdx.x;
    for (int i = tid; i < nbuck; i += 256) hist[i] = 0;
    __syncthreads();

    const int ne4 = ne >> 2;
    const int4* s4 = (const int4*)src;
    const int4* d4 = (const int4*)dst;

    int4 sv[4], dv[4];
    int loc[16], bk[16];
    bool val[4];
#pragma unroll
    for (int k = 0; k < 4; ++k) {
        int idx = blockIdx.x * 1024 + k * 256 + tid;
        val[k] = idx < ne4;
        if (val[k]) { sv[k] = s4[idx]; dv[k] = d4[idx]; }
        else { sv[k] = make_int4(0,0,0,0); dv[k] = make_int4(0,0,0,0); }
    }
#pragma unroll
    for (int k = 0; k < 4; ++k) {
        int dd[4] = { dv[k].x, dv[k].y, dv[k].z, dv[k].w };
#pragma unroll
        for (int j = 0; j < 4; ++j) {
            int b = dd[j] >> BSHIFT;
            bk[k*4+j]  = b;
            loc[k*4+j] = val[k] ? atomicAdd(&hist[b], 1) : 0;
        }
    }
    __syncthreads();
    for (int i = tid; i < nbuck; i += 256)
        base[i] = hist[i] ? atomicAdd(&gcount[i], hist[i]) : 0;
    __syncthreads();
#pragma unroll
    for (int k = 0; k < 4; ++k) {
        if (!val[k]) continue;
        int ss[4] = { sv[k].x, sv[k].y, sv[k].z, sv[k].w };
        int dd[4] = { dv[k].x, dv[k].y, dv[k].z, dv[k].w };
#pragma unroll
        for (int j = 0; j < 4; ++j) {
            int b = bk[k*4+j];
            int p = base[b] + loc[k*4+j];
            if (p < BCAP)
                pairs[(size_t)b * BCAP + p] =
                    ((unsigned)ss[j] << BSHIFT) | (unsigned)(dd[j] & (BNODES-1));
        }
    }
    if (blockIdx.x == 0 && tid == 0) {
        for (int e = ne4 * 4; e < ne; ++e) {
            int b = dst[e] >> BSHIFT;
            int p = atomicAdd(&gcount[b], 1);
            if (p < BCAP)
                pairs[(size_t)b * BCAP + p] =
                    ((unsigned)src[e] << BSHIFT) | (unsigned)(dst[e] & (BNODES-1));
        }
    }
}

// ---------------------------------------------------------------------------
// K3: fused list-build + gather. One block per (bucket, 16-node sub-range).
// blockIdx mapping pins all 8 sub-blocks of a bucket to one XCD
// (blk%8 == bucket%8 under round-robin) so the double pairs-read is L2-hot.
// Two passes over pairs build per-node ushort edge lists in LDS (~2.3KB),
// then 4 waves gather 4 nodes each with the round-7 inner loop.
// ---------------------------------------------------------------------------
__global__ __launch_bounds__(256) void gat_bucket(
    const unsigned* __restrict__ pairs, const int* __restrict__ gcount,
    const uint4* __restrict__ QV, const float4* __restrict__ K4,
    float* __restrict__ out, int n, int nbuck)
{
    __shared__ unsigned short sl[SCAP];
    __shared__ int cl[SUBN], cur[SUBN], off[SUBN + 1];

    const int blk = blockIdx.x;
    const int sub = (blk >> 3) & 7;                 // 0..7
    const int b   = (blk >> 6) * 8 + (blk & 7);     // bucket; blk%8 == b%8
    if (b >= nbuck) return;
    const int tid = threadIdx.x;

    if (tid < SUBN) cl[tid] = 0;
    __syncthreads();

    int m = gcount[b]; if (m > BCAP) m = BCAP;
    const unsigned* pb = pairs + (size_t)b * BCAP;

    for (int i = tid; i < m; i += 256) {
        int dl = pb[i] & (BNODES - 1);
        if ((dl >> 4) == sub) atomicAdd(&cl[dl & (SUBN - 1)], 1);
    }
    __syncthreads();
    if (tid == 0) {
        int acc = 0;
#pragma unroll
        for (int i = 0; i < SUBN; ++i) { off[i] = acc; cur[i] = acc; acc += cl[i]; }
        off[SUBN] = acc;
    }
    __syncthreads();
    for (int i = tid; i < m; i += 256) {
        unsigned p = pb[i];
        int dl = p & (BNODES - 1);
        if ((dl >> 4) == sub) {
            int pos = atomicAdd(&cur[dl & (SUBN - 1)], 1);
            if (pos < SCAP) sl[pos] = (unsigned short)(p >> BSHIFT);
        }
    }
    __syncthreads();

    const int w    = tid >> 6;
    const int lane = tid & 63;
    const int l32  = lane & 31;
    const int g    = lane >> 5;

#pragma unroll
    for (int q = 0; q < SUBN / 4; ++q) {
        int nl   = q * 4 + w;
        int node = b * BNODES + sub * SUBN + nl;
        if (node >= n) continue;

        const int e0  = off[nl];
        const int deg = off[nl + 1] - e0;
        const float4 kd = K4[(size_t)node * 32 + l32];

        float4 acc = make_float4(0.f, 0.f, 0.f, 0.f);
        float  dsum = 0.f;

        const int half0 = (deg + 1) >> 1;
        int j  = e0 + (g ? half0 : 0);
        const int je = e0 + (g ? deg : half0);

        for (; j + 3 < je; j += 4) {
            int s0 = sl[j], s1 = sl[j + 1], s2 = sl[j + 2], s3 = sl[j + 3];
            uint4 w0 = QV[(size_t)s0 * 32 + l32];
            uint4 w1 = QV[(size_t)s1 * 32 + l32];
            uint4 w2 = QV[(size_t)s2 * 32 + l32];
            uint4 w3 = QV[(size_t)s3 * 32 + l32];

            float p0 = qdot(w0, kd), p1 = qdot(w1, kd);
            float p2 = qdot(w2, kd), p3 = qdot(w3, kd);
#pragma unroll
            for (int off2 = 1; off2 < 8; off2 <<= 1) {
                p0 += __shfl_xor(p0, off2, 8);
                p1 += __shfl_xor(p1, off2, 8);
                p2 += __shfl_xor(p2, off2, 8);
                p3 += __shfl_xor(p3, off2, 8);
            }
            float e0f = __expf(p0 > 0.f ? p0 : NEG_SLOPE * p0);
            float e1f = __expf(p1 > 0.f ? p1 : NEG_SLOPE * p1);
            float e2f = __expf(p2 > 0.f ? p2 : NEG_SLOPE * p2);
            float e3f = __expf(p3 > 0.f ? p3 : NEG_SLOPE * p3);
            dsum += (e0f + e1f) + (e2f + e3f);
            vacc(w0, e0f, acc); vacc(w1, e1f, acc);
            vacc(w2, e2f, acc); vacc(w3, e3f, acc);
        }
        for (; j < je; ++j) {
            int s0 = sl[j];
            uint4 w0 = QV[(size_t)s0 * 32 + l32];
            float p0 = qdot(w0, kd);
#pragma unroll
            for (int off2 = 1; off2 < 8; off2 <<= 1) p0 += __shfl_xor(p0, off2, 8);
            float e0f = __expf(p0 > 0.f ? p0 : NEG_SLOPE * p0);
            dsum += e0f;
            vacc(w0, e0f, acc);
        }

        acc.x += __shfl_xor(acc.x, 32, 64);
        acc.y += __shfl_xor(acc.y, 32, 64);
        acc.z += __shfl_xor(acc.z, 32, 64);
        acc.w += __shfl_xor(acc.w, 32, 64);
        dsum  += __shfl_xor(dsum, 32, 64);

        if (g == 0) {
            float inv = 1.f / fmaxf(dsum, 1e-9f);
            float4 o; o.x = acc.x*inv; o.y = acc.y*inv; o.z = acc.z*inv; o.w = acc.w*inv;
            ((float4*)out)[(size_t)node * 32 + l32] = o;
        }
    }
}

extern "C" void kernel_launch(void* const* d_in, const int* in_sizes, int n_in,
                              void* d_out, int out_size, void* d_ws, size_t ws_size,
                              hipStream_t stream) {
    const float* h   = (const float*)d_in[0];
    const int*   src = (const int*)d_in[1];
    const int*   dst = (const int*)d_in[2];
    const float* Wq  = (const float*)d_in[3];
    const float* Wk  = (const float*)d_in[4];
    const float* Wv  = (const float*)d_in[5];
    float* out = (float*)d_out;

    const int n     = in_sizes[0] / IN_DIM;   // 50000
    const int ne    = in_sizes[1];            // 1.6M
    const int nbuck = (n + BNODES - 1) >> BSHIFT;

    // workspace: K f32 | QV f16 | gcount | pairs | Wt  (~64 MB)
    float*          K      = (float*)d_ws;
    unsigned short* QV     = (unsigned short*)(K + (size_t)n * OUTC);
    int*            gcount = (int*)(QV + (size_t)n * 256);
    unsigned*       pairs  = (unsigned*)(gcount + MAXBUCK);
    unsigned short* Wt     = (unsigned short*)(pairs + (size_t)MAXBUCK * BCAP);

    w_prep<<<(NCOLS * IN_DIM + 255) / 256, 256, 0, stream>>>(Wq, Wk, Wv, Wt, gcount);
    gat_proj_mfma<<<(n + 31) / 32, 256, 0, stream>>>(h, Wt, K, QV, n);

    int ne4 = ne >> 2;
    int binblk = (ne4 + 1023) / 1024;
    gat_bin<<<binblk, 256, 0, stream>>>(src, dst, gcount, pairs, ne, nbuck);

    int nb8  = (nbuck + 7) / 8;
    gat_bucket<<<nb8 * 64, 256, 0, stream>>>(pairs, gcount, (const uint4*)QV,
                                             (const float4*)K, out, n, nbuck);
}